// Round 4
// baseline (956.253 us; speedup 1.0000x reference)
//
#include <hip/hip_runtime.h>
#include <hip/hip_bf16.h>
#include <cstdint>
#include <cstddef>

// Problem constants
#define B_   2
#define T_   2048
#define DIM_ 4096
#define H_   32
#define HKV_ 8
#define DH_  128
#define MROWS (B_*T_)    // 4096
#define QKV_LD 6144      // fused QKV row stride (4096 Q + 1024 K + 1024 V)

typedef __bf16 bf16_t;
typedef bf16_t bf16x8 __attribute__((ext_vector_type(8)));
typedef bf16_t bf16x4 __attribute__((ext_vector_type(4)));
typedef float  f32x4  __attribute__((ext_vector_type(4)));

typedef __attribute__((address_space(1))) void gvoid_t;
typedef __attribute__((address_space(3))) void lvoid_t;

__device__ __forceinline__ void gld_lds16(const void* g, void* l) {
  __builtin_amdgcn_global_load_lds((gvoid_t*)g, (lvoid_t*)l, 16, 0, 0);
}

__device__ __forceinline__ f32x4 mfma16(bf16x8 a, bf16x8 b, f32x4 c) {
  return __builtin_amdgcn_mfma_f32_16x16x32_bf16(a, b, c, 0, 0, 0);
}

// ---------------------------------------------------------------------------
// 1) elementwise cast fp32 -> bf16 (X)
// ---------------------------------------------------------------------------
__global__ void cast_f32_bf16(const float* __restrict__ in,
                              bf16_t* __restrict__ out, int n4) {
  int i = blockIdx.x * blockDim.x + threadIdx.x;
  if (i < n4) {
    float4 v = ((const float4*)in)[i];
    bf16x4 o;
    o[0] = (bf16_t)v.x; o[1] = (bf16_t)v.y; o[2] = (bf16_t)v.z; o[3] = (bf16_t)v.w;
    ((bf16x4*)out)[i] = o;
  }
}

// ---------------------------------------------------------------------------
// 2) transpose + cast: in fp32 [K][N] -> out bf16 [N][K]
// ---------------------------------------------------------------------------
__global__ void transpose_cast(const float* __restrict__ in,
                               bf16_t* __restrict__ out, int K, int N) {
  __shared__ float tile[32][33];
  int n0 = blockIdx.x * 32, k0 = blockIdx.y * 32;
  int tx = threadIdx.x, ty = threadIdx.y;
#pragma unroll
  for (int j = 0; j < 4; ++j)
    tile[ty + j*8][tx] = in[(size_t)(k0 + ty + j*8) * N + n0 + tx];
  __syncthreads();
#pragma unroll
  for (int j = 0; j < 4; ++j)
    out[(size_t)(n0 + ty + j*8) * K + k0 + tx] = (bf16_t)tile[tx][ty + j*8];
}

// ---------------------------------------------------------------------------
// 3) bf16 MFMA GEMM, m97 structure: C[M][N] = A[M][K] * BT[N][K]^T
// ---------------------------------------------------------------------------
template <int OUT_F32>
__global__ __launch_bounds__(256, 2)
void gemm_bt(const bf16_t* __restrict__ A, const bf16_t* __restrict__ BT,
             void* __restrict__ C, int M, int N, int K) {
  __shared__ __align__(16) bf16_t Als[128 * 32];
  __shared__ __align__(16) bf16_t Bls[128 * 32];
  const int tid  = threadIdx.x;
  const int wave = tid >> 6, lane = tid & 63;
  const int quad = lane >> 4, l16 = lane & 15;
  const int wm = wave >> 1, wn = wave & 1;
  const int m0 = blockIdx.y * 128, n0 = blockIdx.x * 128;

  f32x4 acc[4][4] = {};

  const int srow = lane >> 2;
  const int scol = (lane & 3) * 8;

  for (int k0 = 0; k0 < K; k0 += 32) {
#pragma unroll
    for (int c = 0; c < 2; ++c) {
      int ch = wave * 2 + c;
      gld_lds16(A + (size_t)(m0 + ch*16 + srow) * K + k0 + scol,
                &Als[ch*512 + srow*32 + scol]);
    }
#pragma unroll
    for (int c = 0; c < 2; ++c) {
      int ch = wave * 2 + c;
      gld_lds16(BT + (size_t)(n0 + ch*16 + srow) * K + k0 + scol,
                &Bls[ch*512 + srow*32 + scol]);
    }
    __syncthreads();

    bf16x8 af[4], bfr[4];
#pragma unroll
    for (int mi = 0; mi < 4; ++mi)
      af[mi] = *(const bf16x8*)&Als[(wm*64 + mi*16 + l16)*32 + quad*8];
#pragma unroll
    for (int ni = 0; ni < 4; ++ni)
      bfr[ni] = *(const bf16x8*)&Bls[(wn*64 + ni*16 + l16)*32 + quad*8];
#pragma unroll
    for (int mi = 0; mi < 4; ++mi)
#pragma unroll
      for (int ni = 0; ni < 4; ++ni)
        acc[mi][ni] = mfma16(af[mi], bfr[ni], acc[mi][ni]);
    __syncthreads();
  }

#pragma unroll
  for (int mi = 0; mi < 4; ++mi)
#pragma unroll
    for (int ni = 0; ni < 4; ++ni)
#pragma unroll
      for (int r = 0; r < 4; ++r) {
        int row = m0 + wm*64 + mi*16 + quad*4 + r;
        int col = n0 + wn*64 + ni*16 + l16;
        if (OUT_F32)
          ((float*)C)[(size_t)row * N + col] = acc[mi][ni][r];
        else
          ((bf16_t*)C)[(size_t)row * N + col] = (bf16_t)acc[mi][ni][r];
      }
}

// ---------------------------------------------------------------------------
// 4) in-place RoPE on bf16 rows of stride ld; head layout [Hn][128] at col h*128
// ---------------------------------------------------------------------------
__global__ void rope_kernel(bf16_t* __restrict__ X, int Hn, int ld, int total) {
  int i = blockIdx.x * blockDim.x + threadIdx.x;
  if (i >= total) return;
  int d   = i & 63;
  int rem = i >> 6;
  int h   = rem % Hn; rem /= Hn;
  int t   = rem % T_;
  int b   = rem / T_;
  size_t base = (size_t)(b * T_ + t) * ld + h * DH_;
  float x1 = (float)X[base + d];
  float x2 = (float)X[base + 64 + d];
  float inv_freq = expf(-(float)d * 0.14391156758f);
  float ang = (float)t * inv_freq;
  float s, c;
  sincosf(ang, &s, &c);
  X[base + d]      = (bf16_t)(x1 * c - x2 * s);
  X[base + 64 + d] = (bf16_t)(x1 * s + x2 * c);
}

// ---------------------------------------------------------------------------
// 5) V transpose: V rows (stride ld) [b][t][kv*128+d] -> VT [b][kv][128][T]
// ---------------------------------------------------------------------------
__global__ void v_transpose(const bf16_t* __restrict__ Vb,
                            bf16_t* __restrict__ VT, int ld) {
  __shared__ bf16_t tile[32][33];
  int t0 = blockIdx.x * 32;
  int d0 = blockIdx.y * 32;
  int bk = blockIdx.z;
  int b = bk >> 3, kv = bk & 7;
  int tx = threadIdx.x, ty = threadIdx.y;
#pragma unroll
  for (int j = 0; j < 4; ++j)
    tile[ty + j*8][tx] =
        Vb[(size_t)(b * T_ + t0 + ty + j*8) * ld + kv*DH_ + d0 + tx];
  __syncthreads();
#pragma unroll
  for (int j = 0; j < 4; ++j)
    VT[((size_t)bk * DH_ + d0 + ty + j*8) * T_ + t0 + tx] = tile[tx][ty + j*8];
}

// ---------------------------------------------------------------------------
// 6) causal flash attention with SPLIT-KV balance. BQ=128, BKV=64, 256 thr.
//    Round-4 (r3 post-mortem: grid==capacity -> no backfill; duration set by
//    the 32-iter qt=15 chain while short blocks drain -> occupancy decay):
//      - work items: qt 0..7 whole (2..16 tiles, direct output);
//        qt 8..15 split into 2 halves of (qt+1) tiles each -> raw f32 O +
//        per-row (m,l) partials, merged by combine_attn.
//      - 1536 blocks > 1024 resident capacity; compile-time LPT item table
//        (descending tile count) -> heavy halves first, light blocks backfill.
//      - partial O scratch = d_out (overwritten later by final GEMM);
//        stats in dead WqT region.
//    Softmax: vote-only max + l-via-MFMA (r3), exp2 domain, defer-max.
// ---------------------------------------------------------------------------
static __device__ const signed char it_qt[24] =
  {7,15,15,14,14, 6,13,13,12,12, 5,11,11,10,10, 4, 9, 9, 8, 8, 3, 2, 1, 0};
static __device__ const signed char it_hf[24] =
  {0, 0, 1, 0, 1, 0, 0, 1, 0, 1, 0, 0, 1, 0, 1, 0, 0, 1, 0, 1, 0, 0, 0, 0};

__global__ __launch_bounds__(256, 2)
void flash_attn(const bf16_t* __restrict__ QKV, const bf16_t* __restrict__ VT,
                bf16_t* __restrict__ Ob, float* __restrict__ Part,
                float* __restrict__ Mbuf, float* __restrict__ Lbuf) {
  __shared__ __align__(16) bf16_t Pls[128 * 72];   // [q][kv], +8 pad

  const int tid = threadIdx.x, wave = tid >> 6, lane = tid & 63;
  const int quad = lane >> 4, l16 = lane & 15;

  // decode: id = item*64 + w ; w -> (kv,b,hsub) with kv = w&7 (XCD affinity)
  const int id   = blockIdx.x;
  const int w    = id & 63;
  const int item = id >> 6;
  const int qt   = it_qt[item];
  const int half = it_hf[item];
  const bool isB = (qt >= 8);
  const int kv = w & 7, b = (w >> 3) & 1;
  const int h  = kv * 4 + (w >> 4);

  const int cnt = isB ? (qt + 1) : 2 * (qt + 1);
  const int kv0 = isB ? half * (qt + 1) : 0;

  // Q fragments (rope already applied): rows wave*32 + mi*16 + l16
  bf16x8 q[2][4];
#pragma unroll
  for (int mi = 0; mi < 2; ++mi) {
    const bf16_t* base =
        QKV + (size_t)(b*T_ + qt*128 + wave*32 + mi*16 + l16) * QKV_LD + h*DH_;
#pragma unroll
    for (int kk = 0; kk < 4; ++kk)
      q[mi][kk] = *(const bf16x8*)(base + kk*32 + quad*8);
  }

  float m_st[2][4];
  f32x4 o_acc[2][8] = {};
  f32x4 l_acc[2] = {};
#pragma unroll
  for (int mi = 0; mi < 2; ++mi)
#pragma unroll
    for (int r = 0; r < 4; ++r) m_st[mi][r] = -1e30f;

  const float S2 = 0.08838834764831845f * 1.4426950408889634f; // sc*log2(e)
  const float THRraw = 8.0f / 0.08838834764831845f;            // defer threshold

  const bf16_t* Kbase = QKV + DIM_ + (size_t)b * T_ * QKV_LD + kv * DH_;
  const bf16_t* Vbase = VT + (size_t)(b*HKV_ + kv) * DH_ * T_;

  bf16x8 vones;
#pragma unroll
  for (int i = 0; i < 8; ++i) vones[i] = (bf16_t)1.0f;

  for (int kvt = kv0; kvt < kv0 + cnt; ++kvt) {
    // ---- S = Q K^T : K fragments straight from global (L2-hot) ----
    f32x4 s[2][4] = {};
#pragma unroll
    for (int kk = 0; kk < 4; ++kk) {
      bf16x8 kf[4];
#pragma unroll
      for (int ni = 0; ni < 4; ++ni) {
        int krow = kvt*64 + ni*16 + l16;
        kf[ni] = *(const bf16x8*)(Kbase + (size_t)krow * QKV_LD + kk*32 + quad*8);
      }
      __builtin_amdgcn_s_setprio(1);
#pragma unroll
      for (int mi = 0; mi < 2; ++mi)
#pragma unroll
        for (int ni = 0; ni < 4; ++ni)
          s[mi][ni] = mfma16(q[mi][kk], kf[ni], s[mi][ni]);
      __builtin_amdgcn_s_setprio(0);
    }

    // ---- causal mask + online softmax (vote-only max; l via MFMA) ----
    const bool need_mask = (kvt >= 2*qt);
#pragma unroll
    for (int mi = 0; mi < 2; ++mi) {
      float lmax[4];
#pragma unroll
      for (int r = 0; r < 4; ++r) {
        int rpos = qt*128 + wave*32 + mi*16 + quad*4 + r;
        float m = -1e30f;
#pragma unroll
        for (int ni = 0; ni < 4; ++ni) {
          float v = s[mi][ni][r];
          if (need_mask) {
            int cpos = kvt*64 + ni*16 + l16;
            if (cpos > rpos) v = -1e30f;
          }
          s[mi][ni][r] = v;
          m = fmaxf(m, v);
        }
        lmax[r] = m;
      }
      bool defer = (lmax[0] <= m_st[mi][0] + THRraw) &
                   (lmax[1] <= m_st[mi][1] + THRraw) &
                   (lmax[2] <= m_st[mi][2] + THRraw) &
                   (lmax[3] <= m_st[mi][3] + THRraw);
      if (!__all(defer)) {
        float al[4];
#pragma unroll
        for (int r = 0; r < 4; ++r) {
          float m = lmax[r];
#pragma unroll
          for (int off = 1; off < 16; off <<= 1)
            m = fmaxf(m, __shfl_xor(m, off, 64));
          float mnew = fmaxf(m_st[mi][r], m);
          al[r] = __builtin_amdgcn_exp2f((m_st[mi][r] - mnew) * S2);
          m_st[mi][r] = mnew;
        }
#pragma unroll
        for (int ni = 0; ni < 8; ++ni)
#pragma unroll
          for (int r = 0; r < 4; ++r) o_acc[mi][ni][r] *= al[r];
#pragma unroll
        for (int r = 0; r < 4; ++r) l_acc[mi][r] *= al[r];
      }
      // exp2 + P write (common path; wave-private rows, no barrier)
#pragma unroll
      for (int r = 0; r < 4; ++r) {
        float mn2 = m_st[mi][r] * S2;
        int prow = wave*32 + mi*16 + quad*4 + r;
#pragma unroll
        for (int ni = 0; ni < 4; ++ni) {
          float pv = __builtin_amdgcn_exp2f(fmaf(s[mi][ni][r], S2, -mn2));
          Pls[prow*72 + ni*16 + l16] = (bf16_t)pv;
        }
      }
    }

    // ---- O += P V ; l += P 1 (MFMA rowsum) ----
    bf16x8 pf[2][2];
#pragma unroll
    for (int kk = 0; kk < 2; ++kk)
#pragma unroll
      for (int mi = 0; mi < 2; ++mi)
        pf[kk][mi] = *(const bf16x8*)&Pls[(wave*32 + mi*16 + l16)*72 + kk*32 + quad*8];

    __builtin_amdgcn_s_setprio(1);
    l_acc[0] = mfma16(pf[0][0], vones, l_acc[0]);
    l_acc[1] = mfma16(pf[0][1], vones, l_acc[1]);
    l_acc[0] = mfma16(pf[1][0], vones, l_acc[0]);
    l_acc[1] = mfma16(pf[1][1], vones, l_acc[1]);
    __builtin_amdgcn_s_setprio(0);

#pragma unroll
    for (int ni = 0; ni < 8; ++ni) {
      int drow = ni*16 + l16;
      const bf16_t* vb = Vbase + (size_t)drow * T_ + kvt*64;
      bf16x8 va = *(const bf16x8*)(vb + quad*8);
      bf16x8 vc = *(const bf16x8*)(vb + 32 + quad*8);
      __builtin_amdgcn_s_setprio(1);
      o_acc[0][ni] = mfma16(pf[0][0], va, o_acc[0][ni]);
      o_acc[1][ni] = mfma16(pf[0][1], va, o_acc[1][ni]);
      o_acc[0][ni] = mfma16(pf[1][0], vc, o_acc[0][ni]);
      o_acc[1][ni] = mfma16(pf[1][1], vc, o_acc[1][ni]);
      __builtin_amdgcn_s_setprio(0);
    }
  }

  if (!isB) {
    // direct epilogue: normalize and store bf16
#pragma unroll
    for (int mi = 0; mi < 2; ++mi) {
      float inv[4];
#pragma unroll
      for (int r = 0; r < 4; ++r) inv[r] = 1.f / l_acc[mi][r];
#pragma unroll
      for (int ni = 0; ni < 8; ++ni)
#pragma unroll
        for (int r = 0; r < 4; ++r) {
          size_t row = (size_t)(b*T_ + qt*128 + wave*32 + mi*16 + quad*4 + r);
          int col = h*DH_ + ni*16 + l16;
          Ob[row * DIM_ + col] = (bf16_t)(o_acc[mi][ni][r] * inv[r]);
        }
    }
  } else {
    // partial epilogue: raw f32 O + per-row stats
    const int i16 = (qt - 8) * 2 + half;
    float* pb = Part + ((size_t)(i16 * 64 + w)) * 128 * 128;
#pragma unroll
    for (int mi = 0; mi < 2; ++mi)
#pragma unroll
      for (int ni = 0; ni < 8; ++ni)
#pragma unroll
        for (int r = 0; r < 4; ++r) {
          int row = wave*32 + mi*16 + quad*4 + r;
          int col = ni*16 + l16;
          pb[row*128 + col] = o_acc[mi][ni][r];
        }
    if (l16 == 0) {
      const int sb = (i16 * 64 + w) * 128;
#pragma unroll
      for (int mi = 0; mi < 2; ++mi)
#pragma unroll
        for (int r = 0; r < 4; ++r) {
          int row = wave*32 + mi*16 + quad*4 + r;
          Mbuf[sb + row] = m_st[mi][r];
          Lbuf[sb + row] = l_acc[mi][r];
        }
    }
  }
}

// ---------------------------------------------------------------------------
// 7) combine two kv-halves for qt 8..15: O = (w0 O0 + w1 O1)/(w0 l0 + w1 l1)
// ---------------------------------------------------------------------------
__global__ void combine_attn(const float* __restrict__ Part,
                             const float* __restrict__ Mbuf,
                             const float* __restrict__ Lbuf,
                             bf16_t* __restrict__ Ob) {
  const int bid = blockIdx.x;           // 512 = 8 qtb * 64 w
  const int qtb = bid >> 6;             // qt = 8 + qtb
  const int w   = bid & 63;
  const int kv = w & 7, b = (w >> 3) & 1;
  const int h  = kv * 4 + (w >> 4);
  const int qt = 8 + qtb;
  const int tid = threadIdx.x;
  const int r  = tid >> 1;
  const int ch = (tid & 1) * 64;

  const int i0 = qtb * 2, i1 = qtb * 2 + 1;
  const float m0 = Mbuf[(i0*64 + w)*128 + r];
  const float m1 = Mbuf[(i1*64 + w)*128 + r];
  const float l0 = Lbuf[(i0*64 + w)*128 + r];
  const float l1 = Lbuf[(i1*64 + w)*128 + r];
  const float mx = fmaxf(m0, m1);
  const float S2 = 0.08838834764831845f * 1.4426950408889634f;
  const float w0 = __builtin_amdgcn_exp2f((m0 - mx) * S2);
  const float w1 = __builtin_amdgcn_exp2f((m1 - mx) * S2);
  const float inv = 1.f / (w0 * l0 + w1 * l1);

  const float* p0 = Part + ((size_t)(i0*64 + w))*128*128 + (size_t)r*128 + ch;
  const float* p1 = Part + ((size_t)(i1*64 + w))*128*128 + (size_t)r*128 + ch;
  bf16_t* op = Ob + (size_t)(b*T_ + qt*128 + r) * DIM_ + h*DH_ + ch;

#pragma unroll
  for (int c = 0; c < 64; c += 4) {
    float4 a = *(const float4*)(p0 + c);
    float4 d = *(const float4*)(p1 + c);
    bf16x4 o;
    o[0] = (bf16_t)((a.x * w0 + d.x * w1) * inv);
    o[1] = (bf16_t)((a.y * w0 + d.y * w1) * inv);
    o[2] = (bf16_t)((a.z * w0 + d.z * w1) * inv);
    o[3] = (bf16_t)((a.w * w0 + d.w * w1) * inv);
    *(bf16x4*)(op + c) = o;
  }
}

// ---------------------------------------------------------------------------
// launch
// ---------------------------------------------------------------------------
extern "C" void kernel_launch(void* const* d_in, const int* in_sizes, int n_in,
                              void* d_out, int out_size, void* d_ws, size_t ws_size,
                              hipStream_t stream) {
  const float* X  = (const float*)d_in[0];
  const float* Wq = (const float*)d_in[1];
  const float* Wk = (const float*)d_in[2];
  const float* Wv = (const float*)d_in[3];
  const float* Wo = (const float*)d_in[4];
  float* out = (float*)d_out;

  // workspace layout (bytes); total ~176.2 MB (same as before)
  char* ws = (char*)d_ws;
  const size_t SZ_X   = (size_t)MROWS * DIM_ * 2;     // 33.55 MB
  const size_t SZ_WQ  = (size_t)DIM_ * DIM_ * 2;      // 33.55 MB
  const size_t SZ_WK  = (size_t)DIM_ * 1024 * 2;      // 8.39 MB
  const size_t SZ_QKV = (size_t)MROWS * QKV_LD * 2;   // 50.33 MB
  bf16_t* Xb  = (bf16_t*)(ws);                        // X bf16; reused as Ob
  bf16_t* WqT = (bf16_t*)(ws + SZ_X);                 // [4096][4096]
  bf16_t* WkT = (bf16_t*)(ws + SZ_X + SZ_WQ);         // [1024][4096]
  bf16_t* WvT = (bf16_t*)(ws + SZ_X + SZ_WQ + SZ_WK); // [1024][4096]
  bf16_t* WoT = (bf16_t*)(ws + SZ_X + SZ_WQ + 2*SZ_WK);
  bf16_t* QKV = (bf16_t*)(ws + SZ_X + 2*SZ_WQ + 2*SZ_WK);  // [4096][6144]
  bf16_t* VT  = (bf16_t*)(ws + SZ_X + 2*SZ_WQ + 2*SZ_WK + SZ_QKV);
  bf16_t* Ob  = Xb;  // X dead after QKV GEMM

  // split-kv scratch: partial O in d_out (1024 x 64KB = 67.1 MB, exactly);
  // stats in dead WqT region (WqT dead after QKV GEMM; 1 MB each).
  float* Part = out;
  float* Mbuf = (float*)WqT;
  float* Lbuf = Mbuf + 16*64*128;

  // 1) casts / transposes
  {
    int n4 = MROWS * DIM_ / 4;
    cast_f32_bf16<<<(n4 + 255)/256, 256, 0, stream>>>(X, Xb, n4);
  }
  transpose_cast<<<dim3(DIM_/32, DIM_/32), dim3(32,8), 0, stream>>>(Wq, WqT, DIM_, DIM_);
  transpose_cast<<<dim3(1024/32, DIM_/32), dim3(32,8), 0, stream>>>(Wk, WkT, DIM_, 1024);
  transpose_cast<<<dim3(1024/32, DIM_/32), dim3(32,8), 0, stream>>>(Wv, WvT, DIM_, 1024);
  transpose_cast<<<dim3(DIM_/32, DIM_/32), dim3(32,8), 0, stream>>>(Wo, WoT, DIM_, DIM_);

  // 2) fused QKV projection: C[4096][6144] = Xb * [Wq|Wk|Wv]
  gemm_bt<0><<<dim3(QKV_LD/128, MROWS/128), 256, 0, stream>>>(Xb, WqT, QKV, MROWS, QKV_LD, DIM_);

  // 3) RoPE (in place, inside fused buffer)
  {
    int totq = B_ * T_ * H_ * 64;
    rope_kernel<<<(totq + 255)/256, 256, 0, stream>>>(QKV, H_, QKV_LD, totq);
    int totk = B_ * T_ * HKV_ * 64;
    rope_kernel<<<(totk + 255)/256, 256, 0, stream>>>(QKV + DIM_, HKV_, QKV_LD, totk);
  }

  // 4) V transpose (V columns live at QKV + 5120)
  v_transpose<<<dim3(T_/32, DH_/32, B_*HKV_), dim3(32,8), 0, stream>>>(QKV + DIM_ + 1024, VT, QKV_LD);

  // 5) flash attention, split-kv LPT grid (24 items x 64 bh)
  flash_attn<<<dim3(24 * 64), 256, 0, stream>>>(QKV, VT, Ob, Part, Mbuf, Lbuf);

  // 6) combine kv-halves for qt 8..15
  combine_attn<<<dim3(8 * 64), 256, 0, stream>>>(Part, Mbuf, Lbuf, Ob);

  // 7) output projection -> fp32 d_out (overwrites Part scratch)
  gemm_bt<1><<<dim3(DIM_/128, MROWS/128), 256, 0, stream>>>(Ob, WoT, out, MROWS, DIM_, DIM_);
}